// Round 18
// baseline (108.746 us; speedup 1.0000x reference)
//
#include <hip/hip_runtime.h>
#include <math.h>

#define Bb 256
#define Ll 20000
#define WPOOL 3999
#define HEADS 5
#define HDIM 30
#define KSPLIT 8
#define NQKV 450            // 3 proj * 5 heads * 30
#define PSTRIDE (NQKV*1024) // one k-split slice: 256 b * 4 s * 450 n floats
#define BQT 4               // batches per k2 block
#define WTRS 480            // WT row stride (floats): 120 thread-slots * 4
#define NB_K1 (Bb*16)       // k1 conv blocks; blocks >= NB_K1 do the W transpose

// workspace layout (float offsets)
#define WS_F    0           // 360: F[t=0..4][d=0..17][i=0..3] (t=4 zero)
#define WS_BIAS 368         // 4: interior bias per row i
#define WS_G    384         // 900: G[p=t0*5+t1][j=0..8][i] = F[t0][2j]+F[t1][2j+1]
#define WS_FBL  1288        // 4*360: left-boundary tables, w=0..3
#define WS_FBR  2728        // 5*360: right-boundary tables, w'=0..4 (w=L-5+w')
#define WS_BBL  4528        // 4*4 left biases
#define WS_BBR  4544        // 5*4 right biases
#define WS_X    4608        // B*WPOOL*4 pooled features, [b][p][i]
#define WS_P    (WS_X + Bb*WPOOL*4)         // KSPLIT slices of qkv partials
#define WS_WT   (WS_P + KSPLIT*PSTRIDE)     // 3999*480 transposed W
// total floats: WS_WT + 3999*480 = 9,705,504 (~37 MiB)

// -------- K0 v4: WP-factored tables, boundary work gridded over 13 blocks ---
__device__ __forceinline__ float tbl_entry(const float* __restrict__ WP,
    int t, int d, int i, int kw2min, int kw2max)
{
    if (t >= 4) return 0.f;
    float p[4] = {0.f, 0.f, 0.f, 0.f};
#pragma unroll
    for (int kh = 0; kh < 4; ++kh) {
        int r = i + kh - 1;
        if (r < 0 || r > 3) continue;
        int kh1 = t - r + 1;
        if (kh1 < 0 || kh1 > 3) continue;
        int lo = d - kw2max; if (lo < 0) lo = 0;
        int hi = d - kw2min; if (hi > 9) hi = 9;
        const float* wpa = WP + (kh1 * 10) * 40 + kh * 10;
        for (int kw1 = lo; kw1 <= hi; ++kw1)
            p[kh] += wpa[kw1 * 40 + (d - kw1)];
    }
    return (p[0] + p[1]) + (p[2] + p[3]);
}

__global__ __launch_bounds__(256) void k0_build(const float* __restrict__ w1g,
    const float* __restrict__ b1g, const float* __restrict__ w2g,
    const float* __restrict__ b2g, float* __restrict__ ws)
{
    __shared__ float w1[200], w2[200], b1[5], WP[1600], SB[40], Fsh[360];
    __shared__ float b2v;
    const int tid = threadIdx.x;

    for (int i = tid; i < 200; i += 256) {
        w1[i] = w1g[i];
        w2[i] = w2g[i];
    }
    if (tid < 5) b1[tid] = b1g[tid];
    if (tid == 5) b2v = b2g[0];
    __syncthreads();

    for (int idx = tid; idx < 1600; idx += 256) {
        int a = idx / 40, b = idx % 40;
        float acc = 0.f;
#pragma unroll
        for (int c = 0; c < 5; ++c) acc += w1[a * 5 + c] * w2[b * 5 + c];
        WP[idx] = acc;
    }
    if (tid < 40) {
        float acc = 0.f;
#pragma unroll
        for (int c = 0; c < 5; ++c) acc += b1[c] * w2[tid * 5 + c];
        SB[tid] = acc;
    }
    __syncthreads();

    if (blockIdx.x == 0) {
        for (int idx = tid; idx < 360; idx += 256) {
            int t = idx / 72, d = (idx / 4) % 18, i = idx % 4;
            float v = tbl_entry(WP, t, d, i, 0, 9);
            Fsh[idx] = v;
            ws[WS_F + idx] = v;
        }
        if (tid < 4) {
            int i = tid;
            float acc = b2v;
#pragma unroll
            for (int kh = 0; kh < 4; ++kh) {
                int r = i + kh - 1;
                if (r < 0 || r > 3) continue;
                for (int kw2 = 0; kw2 < 10; ++kw2) acc += SB[kh * 10 + kw2];
            }
            ws[WS_BIAS + i] = acc;
        }
        __syncthreads();
        for (int idx = tid; idx < 900; idx += 256) {
            int p = idx / 36, j = (idx / 4) % 9, i = idx % 4;
            int t0 = p / 5, t1 = p % 5;
            ws[WS_G + idx] = Fsh[(t0 * 18 + 2 * j) * 4 + i]
                           + Fsh[(t1 * 18 + 2 * j + 1) * 4 + i];
        }
    } else {
        int gidx = (blockIdx.x - 1) * 256 + tid;
        if (gidx < 3240) {
            int wslot = gidx / 360, rem = gidx % 360;
            int t = rem / 72, d = (rem / 4) % 18, i = rem % 4;
            bool left = wslot < 4;
            int wloc = left ? wslot : wslot - 4;
            int kw2min = left ? 4 - wloc : 0;
            int kw2max = left ? 9 : 8 - wloc;
            float v = tbl_entry(WP, t, d, i, kw2min, kw2max);
            ws[(left ? WS_FBL + wloc * 360 : WS_FBR + wloc * 360) + rem] = v;
        } else if (gidx < 3276) {
            int bs = gidx - 3240;
            int wslot = bs / 4, i = bs % 4;
            bool left = wslot < 4;
            int wloc = left ? wslot : wslot - 4;
            int kw2min = left ? 4 - wloc : 0;
            int kw2max = left ? 9 : 8 - wloc;
            float acc = b2v;
#pragma unroll
            for (int kh = 0; kh < 4; ++kh) {
                int r = i + kh - 1;
                if (r < 0 || r > 3) continue;
                for (int kw2 = kw2min; kw2 <= kw2max; ++kw2)
                    acc += SB[kh * 10 + kw2];
            }
            ws[(left ? WS_BBL + wloc * 4 : WS_BBR + wloc * 4) + i] = acc;
        }
    }
}

// -------- K1 (+ merged W-transpose) -----------------------------------------
__global__ __launch_bounds__(256) void k1_convpool(const int* __restrict__ tokens,
    const float* __restrict__ Wq, const float* __restrict__ Wk,
    const float* __restrict__ Wv, const float* __restrict__ ws_c,
    float* __restrict__ ws)
{
    __shared__ int tok[1280];
    __shared__ float4 Gs[225];
    __shared__ float4 m5[256];
    __shared__ float4 biasS;

    const int tid = threadIdx.x;

    if (blockIdx.x >= NB_K1) {
        int idx = (blockIdx.x - NB_K1) * 256 + tid;
        if (idx < WPOOL * WTRS) {
            int k = idx / WTRS, slot = idx % WTRS;
            int t = slot >> 2, c = slot & 3;
            int ph = t >> 3, j = t & 7;
            int proj = ph / 5, hh = ph % 5;
            float v = 0.f;
            int e = (j < 7) ? 4 * j + c : 28 + c;
            if (e < 30) {
                const float* Wm = (proj == 0) ? Wq : ((proj == 1) ? Wk : Wv);
                v = Wm[(size_t)hh * WPOOL * 30 + (size_t)k * 30 + e];
            }
            ws[WS_WT + idx] = v;
        }
        return;
    }

    const int b = blockIdx.x >> 4;
    const int chunk = blockIdx.x & 15;
    const int p0 = chunk * 250;
    const int pcnt = min(250, WPOOL - p0);
    const int colBase = 5 * p0 - 8;

    const float4* Gg = reinterpret_cast<const float4*>(ws_c + WS_G);
    for (int j = tid; j < 225; j += 256) Gs[j] = Gg[j];
    if (tid == 0) biasS = *reinterpret_cast<const float4*>(ws_c + WS_BIAS);
    const int* tb = tokens + (size_t)b * Ll;
    for (int j = tid; j < 1280; j += 256) {
        int u = colBase + j;
        tok[j] = (u >= 0 && u < Ll) ? tb[u] : 4;
    }
    __syncthreads();

    if (tid <= pcnt) {
        const int W = 5 * (p0 + tid);
        int tk[22];
#pragma unroll
        for (int m = 0; m < 22; ++m) tk[m] = tok[5 * tid + m];

        float4 mymax;
        const bool isLeft = (chunk == 0 && tid == 0);
        const bool isRight = (W + 4 >= Ll - 5);
        if (!isLeft && !isRight) {
            float4 bias4 = biasS;
            bool first = true;
#pragma unroll
            for (int c = 0; c < 5; ++c) {
                float a0 = bias4.x, a1 = bias4.y, a2 = bias4.z, a3 = bias4.w;
#pragma unroll
                for (int j = 0; j < 9; ++j) {
                    int pc = tk[c + 2 * j] * 5 + tk[c + 2 * j + 1];
                    float4 g = Gs[pc * 9 + j];
                    a0 += g.x; a1 += g.y; a2 += g.z; a3 += g.w;
                }
                if (first) { mymax = make_float4(a0, a1, a2, a3); first = false; }
                else {
                    mymax.x = fmaxf(mymax.x, a0); mymax.y = fmaxf(mymax.y, a1);
                    mymax.z = fmaxf(mymax.z, a2); mymax.w = fmaxf(mymax.w, a3);
                }
            }
        } else {
            bool first = true;
            for (int c = 0; c < 5; ++c) {
                int w = W + c;
                const float* T; const float* Bv;
                if (w < 4)            { T = ws_c + WS_FBL + w * 360;           Bv = ws_c + WS_BBL + 4 * w; }
                else if (w >= Ll - 5) { T = ws_c + WS_FBR + (w - (Ll - 5)) * 360; Bv = ws_c + WS_BBR + 4 * (w - (Ll - 5)); }
                else                  { T = ws_c + WS_F;                        Bv = ws_c + WS_BIAS; }
                float a0 = Bv[0], a1 = Bv[1], a2 = Bv[2], a3 = Bv[3];
                for (int d = 0; d < 18; ++d) {
                    const float* f = T + (size_t)(tk[c + d] * 18 + d) * 4;
                    a0 += f[0]; a1 += f[1]; a2 += f[2]; a3 += f[3];
                }
                if (first) { mymax = make_float4(a0, a1, a2, a3); first = false; }
                else {
                    mymax.x = fmaxf(mymax.x, a0); mymax.y = fmaxf(mymax.y, a1);
                    mymax.z = fmaxf(mymax.z, a2); mymax.w = fmaxf(mymax.w, a3);
                }
            }
        }
        m5[tid] = mymax;
    }
    __syncthreads();

    if (tid < pcnt) {
        float4 a = m5[tid], c = m5[tid + 1];
        a.x = fmaxf(a.x, c.x); a.y = fmaxf(a.y, c.y);
        a.z = fmaxf(a.z, c.z); a.w = fmaxf(a.w, c.w);
        reinterpret_cast<float4*>(ws + WS_X)[(size_t)b * WPOOL + p0 + tid] = a;
    }
}

// -------- K2 v13: 1024-thread blocks, 8-group k-split -----------------------
// Same 512 blocks (bt-major, BQT=4, scalar x, 4-slot W prefetch) but 16
// waves/block -> 32 waves/CU: restores the TLP that BQT=4 gave up, keeping
// its halved W traffic. Group g covers k-range [(g*kn)/8, ((g+1)*kn)/8)
// (62-63 steps). Cross-group combine: sequential 7-pass through the same
// 31.2 KB odd-stride scratch.
__global__ __launch_bounds__(1024) void k2_qkv(const float* __restrict__ xbuf,
    const float* __restrict__ wtbuf, float* __restrict__ ws)
{
    __shared__ float red[120 * 65];          // 31200 B reduce scratch
    const int tid = threadIdx.x;
    const int ks = blockIdx.x & 7;           // bt-major: adjacent blocks share x
    const int bt = blockIdx.x >> 3;
    const int bq0 = bt * BQT;
    const int k0 = ks * 500;
    const int kn = min(500, WPOOL - k0);     // 500, except 499 for ks=7

    const int grp = tid >> 7;                // 0..7 (uniform within a wave)
    const int t = tid & 127;
    const int g = __builtin_amdgcn_readfirstlane(grp);   // SGPR-uniform
    const int gk0 = (g * kn) >> 3;
    const int gend = ((g + 1) * kn) >> 3;    // group size 62..63

    const int ph = t >> 3, j = t & 7;
    const int proj = ph / 5, hh = ph % 5;
    const int e0 = (j < 7) ? 4 * j : 28;
    const bool quad = (j < 7);
    const float* wt = wtbuf + (size_t)k0 * WTRS + 4 * t;
    const float4* xg[BQT];
#pragma unroll
    for (int b = 0; b < BQT; ++b)
        xg[b] = reinterpret_cast<const float4*>(xbuf)
                + (size_t)(bq0 + b) * WPOOL + k0;

    float acc[BQT][4][4] = {};

#define FMA_STEP(KIDX, W) do {                                       \
        _Pragma("unroll")                                            \
        for (int b = 0; b < BQT; ++b) {                              \
            float4 xv = xg[b][KIDX];                                 \
            acc[b][0][0] = fmaf(xv.x, W.x, acc[b][0][0]);            \
            acc[b][1][0] = fmaf(xv.y, W.x, acc[b][1][0]);            \
            acc[b][2][0] = fmaf(xv.z, W.x, acc[b][2][0]);            \
            acc[b][3][0] = fmaf(xv.w, W.x, acc[b][3][0]);            \
            acc[b][0][1] = fmaf(xv.x, W.y, acc[b][0][1]);            \
            acc[b][1][1] = fmaf(xv.y, W.y, acc[b][1][1]);            \
            acc[b][2][1] = fmaf(xv.z, W.y, acc[b][2][1]);            \
            acc[b][3][1] = fmaf(xv.w, W.y, acc[b][3][1]);            \
            acc[b][0][2] = fmaf(xv.x, W.z, acc[b][0][2]);            \
            acc[b][1][2] = fmaf(xv.y, W.z, acc[b][1][2]);            \
            acc[b][2][2] = fmaf(xv.z, W.z, acc[b][2][2]);            \
            acc[b][3][2] = fmaf(xv.w, W.z, acc[b][3][2]);            \
            acc[b][0][3] = fmaf(xv.x, W.w, acc[b][0][3]);            \
            acc[b][1][3] = fmaf(xv.y, W.w, acc[b][1][3]);            \
            acc[b][2][3] = fmaf(xv.z, W.w, acc[b][2][3]);            \
            acc[b][3][3] = fmaf(xv.w, W.w, acc[b][3][3]);            \
        }                                                            \
    } while (0)

    if (t < 120) {
        float4 wv[4];
#pragma unroll
        for (int i = 0; i < 4; ++i)          // group size >= 62: in range
            wv[i] = *reinterpret_cast<const float4*>(wt + (size_t)(gk0 + i) * WTRS);

        int kk = gk0;
        for (; kk + 4 <= gend; kk += 4) {
#pragma unroll
            for (int i = 0; i < 4; ++i) {
                float4 W = wv[i];
                int nidx = kk + 4 + i;
                int ncl = nidx < gend ? nidx : gend - 1;   // clamp (unused-safe)
                wv[i] = *reinterpret_cast<const float4*>(wt + (size_t)ncl * WTRS);
                FMA_STEP(kk + i, W);
            }
        }
        for (; kk < gend; ++kk) {            // <=3 direct iterations
            float4 W = *reinterpret_cast<const float4*>(wt + (size_t)kk * WTRS);
            FMA_STEP(kk, W);
        }
    }
#undef FMA_STEP

    // sequential 7-pass cross-group reduce; odd stride 65 -> conflict-free
    __syncthreads();
#pragma unroll
    for (int gg = 1; gg < 8; ++gg) {
        if (grp == gg && t < 120) {
#pragma unroll
            for (int b = 0; b < BQT; ++b)
#pragma unroll
                for (int s = 0; s < 4; ++s)
#pragma unroll
                    for (int jj = 0; jj < 4; ++jj)
                        red[t * 65 + b * 16 + s * 4 + jj] = acc[b][s][jj];
        }
        __syncthreads();
        if (grp == 0 && t < 120) {
#pragma unroll
            for (int b = 0; b < BQT; ++b)
#pragma unroll
                for (int s = 0; s < 4; ++s)
#pragma unroll
                    for (int jj = 0; jj < 4; ++jj)
                        acc[b][s][jj] += red[t * 65 + b * 16 + s * 4 + jj];
        }
        __syncthreads();
    }

    if (grp == 0 && t < 120) {
        const int n0 = proj * 150 + hh * 30 + e0;
        float* Pb = ws + WS_P + (size_t)ks * PSTRIDE;
#pragma unroll
        for (int b = 0; b < BQT; ++b) {
#pragma unroll
            for (int s = 0; s < 4; ++s) {
                float* p = Pb + (size_t)(bq0 + b) * 1800 + s * 450 + n0;
                reinterpret_cast<float2*>(p)[0] = make_float2(acc[b][s][0], acc[b][s][1]);
                if (quad)
                    reinterpret_cast<float2*>(p + 2)[0] = make_float2(acc[b][s][2], acc[b][s][3]);
            }
        }
    }
}

// -------- K3: attention (S=4 causal) + Wo + dense head ---------------------
__global__ __launch_bounds__(256) void k3_attn(const float* __restrict__ Wo,
    const float* __restrict__ d1w, const float* __restrict__ d1b,
    const float* __restrict__ d2w, const float* __restrict__ d2b,
    const float* __restrict__ d3w, const float* __restrict__ d3b,
    const float* __restrict__ ws, float* __restrict__ out)
{
    __shared__ float Qs[5][4][30], Ks2[5][4][30], Vs[5][4][30];
    __shared__ float sc[5][4][4];
    __shared__ float ob[4][150];
    __shared__ float hb[120], h1[10], h2[10];
    const int tid = threadIdx.x;
    const int b = blockIdx.x;
    const float* P = ws + WS_P + (size_t)b * 1800;

    for (int idx = tid; idx < 1800; idx += 256) {
        float val = 0.f;
#pragma unroll
        for (int ks = 0; ks < KSPLIT; ++ks)
            val += P[(size_t)ks * PSTRIDE + idx];
        int s = idx / 450, n = idx % 450;
        int proj = n / 150, hh = (n % 150) / 30, e = n % 30;
        if (proj == 0)      Qs[hh][s][e] = val;
        else if (proj == 1) Ks2[hh][s][e] = val;
        else                Vs[hh][s][e] = val;
    }
    __syncthreads();

    if (tid < 80) {
        int hh = tid >> 4, s = (tid >> 2) & 3, t = tid & 3;
        float a = 0.f;
        if (t <= s) {
            for (int e = 0; e < 30; ++e) a += Qs[hh][s][e] * Ks2[hh][t][e];
            a *= (1.0f / sqrtf(30.0f));
        }
        sc[hh][s][t] = a;
    }
    __syncthreads();

    if (tid < 20) {
        int hh = tid / 4, s = tid % 4;
        float m = -1e30f;
        for (int t = 0; t <= s; ++t) m = fmaxf(m, sc[hh][s][t]);
        float ex[4]; float den = 0.f;
        for (int t = 0; t <= s; ++t) { ex[t] = expf(sc[hh][s][t] - m); den += ex[t]; }
        for (int t = 0; t < 4; ++t) sc[hh][s][t] = (t <= s) ? ex[t] / den : 0.f;
    }
    __syncthreads();

    for (int idx = tid; idx < 600; idx += 256) {
        int s = idx / 150, j = idx % 150, hh = j / 30, e = j % 30;
        float a = 0.f;
        for (int t = 0; t < 4; ++t) a += sc[hh][s][t] * Vs[hh][t][e];
        ob[s][j] = a;
    }
    __syncthreads();

    if (tid < 120) {
        int s = tid / 30, e2 = tid % 30;
        float a = 0.f;
        for (int j = 0; j < 150; ++j) a += ob[s][j] * Wo[j * 30 + e2];
        hb[s * 30 + e2] = a;
    }
    __syncthreads();

    if (tid < 10) {
        float a = d1b[tid];
        for (int i = 0; i < 120; ++i) a += hb[i] * d1w[i * 10 + tid];
        h1[tid] = a > 0.f ? a : 0.2f * a;
    }
    __syncthreads();
    if (tid < 10) {
        float a = d2b[tid];
        for (int i = 0; i < 10; ++i) a += h1[i] * d2w[i * 10 + tid];
        h2[tid] = a > 0.f ? a : 0.2f * a;
    }
    __syncthreads();
    if (tid == 0) {
        float a = d3b[0];
        for (int i = 0; i < 10; ++i) a += h2[i] * d3w[i];
        out[b] = 1.f / (1.f + expf(-a));
    }
}

extern "C" void kernel_launch(void* const* d_in, const int* in_sizes, int n_in,
                              void* d_out, int out_size, void* d_ws, size_t ws_size,
                              hipStream_t stream)
{
    const int*   tokens = (const int*)d_in[0];
    const float* c1w = (const float*)d_in[1];
    const float* c1b = (const float*)d_in[2];
    const float* c2w = (const float*)d_in[3];
    const float* c2b = (const float*)d_in[4];
    const float* Wq  = (const float*)d_in[5];
    const float* Wk  = (const float*)d_in[6];
    const float* Wv  = (const float*)d_in[7];
    const float* Wo  = (const float*)d_in[8];
    const float* d1w = (const float*)d_in[9];
    const float* d1b = (const float*)d_in[10];
    const float* d2w = (const float*)d_in[11];
    const float* d2b = (const float*)d_in[12];
    const float* d3w = (const float*)d_in[13];
    const float* d3b = (const float*)d_in[14];
    float* ws = (float*)d_ws;
    float* out = (float*)d_out;

    const int transwBlocks = (WPOOL * WTRS + 255) / 256;
    k0_build<<<14, 256, 0, stream>>>(c1w, c1b, c2w, c2b, ws);
    k1_convpool<<<NB_K1 + transwBlocks, 256, 0, stream>>>(tokens, Wq, Wk, Wv, ws, ws);
    k2_qkv<<<(Bb / BQT) * KSPLIT, 1024, 0, stream>>>(ws + WS_X, ws + WS_WT, ws);
    k3_attn<<<Bb, 256, 0, stream>>>(Wo, d1w, d1b, d2w, d2b, d3w, d3b, ws, out);
}

// Round 19
// 101.096 us; speedup vs baseline: 1.0757x; 1.0757x over previous
//
#include <hip/hip_runtime.h>
#include <math.h>

#define Bb 256
#define Ll 20000
#define WPOOL 3999
#define HEADS 5
#define HDIM 30
#define NB_K1 (Bb*16)       // k1 conv blocks
#define WBBLK 960           // WB build blocks (480*512/256)
#define PADABLK 388         // A k-pad zero blocks (1024*97/256)
#define MKS 4               // MFMA K-split
#define PS2 (Bb*1800)       // one qkv partial slice: [b][s*450+n]

// workspace layout (float offsets)
#define WS_F    0           // 360: F tables
#define WS_BIAS 368
#define WS_G    384         // 900 pair table
#define WS_FBL  1288
#define WS_FBR  2728
#define WS_BBL  4528
#define WS_BBR  4544
#define WS_X    4608                      // B*WPOOL*4 pooled floats [b][p][s]
#define WS_P    (WS_X + Bb*WPOOL*4)       // MKS * PS2 qkv partials
#define WS_A    (WS_P + MKS*PS2)          // A_bf16 [1024][4096] (ushort)
#define WS_WB   (WS_A + 1024*4096/2)      // WB_bf16 [480][4096] (ushort)
// total floats: WS_WB + 480*4096/2 = 9,022,976 (~36.1 MiB)

typedef short short8 __attribute__((ext_vector_type(8)));
typedef float f32x4 __attribute__((ext_vector_type(4)));

__device__ __forceinline__ unsigned short f2bf(float f) {
    unsigned u = __float_as_uint(f);
    return (unsigned short)((u + 0x7FFFu + ((u >> 16) & 1u)) >> 16);
}

// -------- K0: WP-factored conv tables (unchanged) ---------------------------
__device__ __forceinline__ float tbl_entry(const float* __restrict__ WP,
    int t, int d, int i, int kw2min, int kw2max)
{
    if (t >= 4) return 0.f;
    float p[4] = {0.f, 0.f, 0.f, 0.f};
#pragma unroll
    for (int kh = 0; kh < 4; ++kh) {
        int r = i + kh - 1;
        if (r < 0 || r > 3) continue;
        int kh1 = t - r + 1;
        if (kh1 < 0 || kh1 > 3) continue;
        int lo = d - kw2max; if (lo < 0) lo = 0;
        int hi = d - kw2min; if (hi > 9) hi = 9;
        const float* wpa = WP + (kh1 * 10) * 40 + kh * 10;
        for (int kw1 = lo; kw1 <= hi; ++kw1)
            p[kh] += wpa[kw1 * 40 + (d - kw1)];
    }
    return (p[0] + p[1]) + (p[2] + p[3]);
}

__global__ __launch_bounds__(256) void k0_build(const float* __restrict__ w1g,
    const float* __restrict__ b1g, const float* __restrict__ w2g,
    const float* __restrict__ b2g, float* __restrict__ ws)
{
    __shared__ float w1[200], w2[200], b1[5], WP[1600], SB[40], Fsh[360];
    __shared__ float b2v;
    const int tid = threadIdx.x;

    for (int i = tid; i < 200; i += 256) {
        w1[i] = w1g[i];
        w2[i] = w2g[i];
    }
    if (tid < 5) b1[tid] = b1g[tid];
    if (tid == 5) b2v = b2g[0];
    __syncthreads();

    for (int idx = tid; idx < 1600; idx += 256) {
        int a = idx / 40, b = idx % 40;
        float acc = 0.f;
#pragma unroll
        for (int c = 0; c < 5; ++c) acc += w1[a * 5 + c] * w2[b * 5 + c];
        WP[idx] = acc;
    }
    if (tid < 40) {
        float acc = 0.f;
#pragma unroll
        for (int c = 0; c < 5; ++c) acc += b1[c] * w2[tid * 5 + c];
        SB[tid] = acc;
    }
    __syncthreads();

    if (blockIdx.x == 0) {
        for (int idx = tid; idx < 360; idx += 256) {
            int t = idx / 72, d = (idx / 4) % 18, i = idx % 4;
            float v = tbl_entry(WP, t, d, i, 0, 9);
            Fsh[idx] = v;
            ws[WS_F + idx] = v;
        }
        if (tid < 4) {
            int i = tid;
            float acc = b2v;
#pragma unroll
            for (int kh = 0; kh < 4; ++kh) {
                int r = i + kh - 1;
                if (r < 0 || r > 3) continue;
                for (int kw2 = 0; kw2 < 10; ++kw2) acc += SB[kh * 10 + kw2];
            }
            ws[WS_BIAS + i] = acc;
        }
        __syncthreads();
        for (int idx = tid; idx < 900; idx += 256) {
            int p = idx / 36, j = (idx / 4) % 9, i = idx % 4;
            int t0 = p / 5, t1 = p % 5;
            ws[WS_G + idx] = Fsh[(t0 * 18 + 2 * j) * 4 + i]
                           + Fsh[(t1 * 18 + 2 * j + 1) * 4 + i];
        }
    } else {
        int gidx = (blockIdx.x - 1) * 256 + tid;
        if (gidx < 3240) {
            int wslot = gidx / 360, rem = gidx % 360;
            int t = rem / 72, d = (rem / 4) % 18, i = rem % 4;
            bool left = wslot < 4;
            int wloc = left ? wslot : wslot - 4;
            int kw2min = left ? 4 - wloc : 0;
            int kw2max = left ? 9 : 8 - wloc;
            float v = tbl_entry(WP, t, d, i, kw2min, kw2max);
            ws[(left ? WS_FBL + wloc * 360 : WS_FBR + wloc * 360) + rem] = v;
        } else if (gidx < 3276) {
            int bs = gidx - 3240;
            int wslot = bs / 4, i = bs % 4;
            bool left = wslot < 4;
            int wloc = left ? wslot : wslot - 4;
            int kw2min = left ? 4 - wloc : 0;
            int kw2max = left ? 9 : 8 - wloc;
            float acc = b2v;
#pragma unroll
            for (int kh = 0; kh < 4; ++kh) {
                int r = i + kh - 1;
                if (r < 0 || r > 3) continue;
                for (int kw2 = kw2min; kw2 <= kw2max; ++kw2)
                    acc += SB[kh * 10 + kw2];
            }
            ws[(left ? WS_BBL + wloc * 4 : WS_BBR + wloc * 4) + i] = acc;
        }
    }
}

// -------- K1: conv+pool (writes x fp32 AND A bf16) + WB build + A pad -------
__global__ __launch_bounds__(256) void k1_convpool(const int* __restrict__ tokens,
    const float* __restrict__ Wq, const float* __restrict__ Wk,
    const float* __restrict__ Wv, const float* __restrict__ ws_c,
    float* __restrict__ ws)
{
    __shared__ int tok[1280];
    __shared__ float4 Gs[225];
    __shared__ float4 m5[256];
    __shared__ float4 biasS;

    const int tid = threadIdx.x;

    if (blockIdx.x >= NB_K1) {
        int xb = blockIdx.x - NB_K1;
        unsigned short* Au = reinterpret_cast<unsigned short*>(ws + WS_A);
        unsigned short* WBu = reinterpret_cast<unsigned short*>(ws + WS_WB);
        if (xb < WBBLK) {
            // WB_bf16[n][k], n-major, 8 k per thread
            int idx = xb * 256 + tid;          // 0..245759
            int n = idx >> 9;                  // 0..479
            int k0 = (idx & 511) * 8;
            unsigned short vals[8];
            if (n < 450) {
                int proj = n / 150, hh = (n % 150) / 30, e = n % 30;
                const float* Wm = (proj == 0) ? Wq : ((proj == 1) ? Wk : Wv);
                const float* base = Wm + (size_t)hh * WPOOL * 30 + e;
#pragma unroll
                for (int j = 0; j < 8; ++j) {
                    int k = k0 + j;
                    vals[j] = (k < WPOOL) ? f2bf(base[(size_t)k * 30]) : (unsigned short)0;
                }
            } else {
#pragma unroll
                for (int j = 0; j < 8; ++j) vals[j] = 0;
            }
            unsigned w0 = (unsigned)vals[0] | ((unsigned)vals[1] << 16);
            unsigned w1 = (unsigned)vals[2] | ((unsigned)vals[3] << 16);
            unsigned w2 = (unsigned)vals[4] | ((unsigned)vals[5] << 16);
            unsigned w3 = (unsigned)vals[6] | ((unsigned)vals[7] << 16);
            *reinterpret_cast<uint4*>(WBu + (size_t)n * 4096 + k0) =
                make_uint4(w0, w1, w2, w3);
        } else {
            // zero A[row][3999..4095]
            int idx = (xb - WBBLK) * 256 + tid;
            if (idx < 1024 * 97) {
                int row = idx / 97;
                int kk = WPOOL + idx % 97;
                Au[(size_t)row * 4096 + kk] = 0;
            }
        }
        return;
    }

    const int b = blockIdx.x >> 4;
    const int chunk = blockIdx.x & 15;
    const int p0 = chunk * 250;
    const int pcnt = min(250, WPOOL - p0);
    const int colBase = 5 * p0 - 8;

    const float4* Gg = reinterpret_cast<const float4*>(ws_c + WS_G);
    for (int j = tid; j < 225; j += 256) Gs[j] = Gg[j];
    if (tid == 0) biasS = *reinterpret_cast<const float4*>(ws_c + WS_BIAS);
    const int* tb = tokens + (size_t)b * Ll;
    for (int j = tid; j < 1280; j += 256) {
        int u = colBase + j;
        tok[j] = (u >= 0 && u < Ll) ? tb[u] : 4;
    }
    __syncthreads();

    if (tid <= pcnt) {
        const int W = 5 * (p0 + tid);
        int tk[22];
#pragma unroll
        for (int m = 0; m < 22; ++m) tk[m] = tok[5 * tid + m];

        float4 mymax;
        const bool isLeft = (chunk == 0 && tid == 0);
        const bool isRight = (W + 4 >= Ll - 5);
        if (!isLeft && !isRight) {
            float4 bias4 = biasS;
            bool first = true;
#pragma unroll
            for (int c = 0; c < 5; ++c) {
                float a0 = bias4.x, a1 = bias4.y, a2 = bias4.z, a3 = bias4.w;
#pragma unroll
                for (int j = 0; j < 9; ++j) {
                    int pc = tk[c + 2 * j] * 5 + tk[c + 2 * j + 1];
                    float4 g = Gs[pc * 9 + j];
                    a0 += g.x; a1 += g.y; a2 += g.z; a3 += g.w;
                }
                if (first) { mymax = make_float4(a0, a1, a2, a3); first = false; }
                else {
                    mymax.x = fmaxf(mymax.x, a0); mymax.y = fmaxf(mymax.y, a1);
                    mymax.z = fmaxf(mymax.z, a2); mymax.w = fmaxf(mymax.w, a3);
                }
            }
        } else {
            bool first = true;
            for (int c = 0; c < 5; ++c) {
                int w = W + c;
                const float* T; const float* Bv;
                if (w < 4)            { T = ws_c + WS_FBL + w * 360;           Bv = ws_c + WS_BBL + 4 * w; }
                else if (w >= Ll - 5) { T = ws_c + WS_FBR + (w - (Ll - 5)) * 360; Bv = ws_c + WS_BBR + 4 * (w - (Ll - 5)); }
                else                  { T = ws_c + WS_F;                        Bv = ws_c + WS_BIAS; }
                float a0 = Bv[0], a1 = Bv[1], a2 = Bv[2], a3 = Bv[3];
                for (int d = 0; d < 18; ++d) {
                    const float* f = T + (size_t)(tk[c + d] * 18 + d) * 4;
                    a0 += f[0]; a1 += f[1]; a2 += f[2]; a3 += f[3];
                }
                if (first) { mymax = make_float4(a0, a1, a2, a3); first = false; }
                else {
                    mymax.x = fmaxf(mymax.x, a0); mymax.y = fmaxf(mymax.y, a1);
                    mymax.z = fmaxf(mymax.z, a2); mymax.w = fmaxf(mymax.w, a3);
                }
            }
        }
        m5[tid] = mymax;
    }
    __syncthreads();

    if (tid < pcnt) {
        float4 a = m5[tid], c = m5[tid + 1];
        a.x = fmaxf(a.x, c.x); a.y = fmaxf(a.y, c.y);
        a.z = fmaxf(a.z, c.z); a.w = fmaxf(a.w, c.w);
        const int k = p0 + tid;
        reinterpret_cast<float4*>(ws + WS_X)[(size_t)b * WPOOL + k] = a;
        // bf16 A rows m = b*4 + s (coalesced per s-row across tid)
        unsigned short* Au = reinterpret_cast<unsigned short*>(ws + WS_A);
        Au[(size_t)(b * 4 + 0) * 4096 + k] = f2bf(a.x);
        Au[(size_t)(b * 4 + 1) * 4096 + k] = f2bf(a.y);
        Au[(size_t)(b * 4 + 2) * 4096 + k] = f2bf(a.z);
        Au[(size_t)(b * 4 + 3) * 4096 + k] = f2bf(a.w);
    }
}

// -------- K2 v14: bf16 MFMA GEMM, M=1024 N=480 K=4096, K-split=4 ------------
// Wave = one 16-row m-tile x five 16-col n-tiles x K-slice 1024 (32 MFMA
// steps, 5-deep independent MFMA chains). Frag layouts per guide §3 (m89):
// A: row=lane&15, k=(lane>>4)*8+j; B: col=lane&15, same k; D: col=lane&15,
// row=(lane>>4)*4+reg. Grid (mg innermost) so adjacent blocks share B in L2.
__global__ __launch_bounds__(256) void k2_mfma(const unsigned short* __restrict__ A,
    const unsigned short* __restrict__ WB, float* __restrict__ P)
{
    const int wave = threadIdx.x >> 6;
    const int lane = threadIdx.x & 63;
    const int mg = blockIdx.x & 15;
    const int rest = blockIdx.x >> 4;
    const int ng = rest % 6;
    const int ks = rest / 6;
    const int m0 = (mg * 4 + wave) * 16;
    const int n0 = ng * 80;
    const int kbase = ks * 1024;

    const int lrow = lane & 15;
    const int lk = (lane >> 4) * 8;

    const unsigned short* Ap = A + (size_t)(m0 + lrow) * 4096 + kbase + lk;
    const unsigned short* Bp = WB + (size_t)(n0 + lrow) * 4096 + kbase + lk;

    f32x4 acc0 = {0.f, 0.f, 0.f, 0.f};
    f32x4 acc1 = acc0, acc2 = acc0, acc3 = acc0, acc4 = acc0;

#pragma unroll 4
    for (int step = 0; step < 32; ++step) {
        const unsigned short* ap = Ap + step * 32;
        const unsigned short* bp = Bp + step * 32;
        short8 af = *reinterpret_cast<const short8*>(ap);
        short8 b0 = *reinterpret_cast<const short8*>(bp);
        short8 b1 = *reinterpret_cast<const short8*>(bp + (size_t)16 * 4096);
        short8 b2 = *reinterpret_cast<const short8*>(bp + (size_t)32 * 4096);
        short8 b3 = *reinterpret_cast<const short8*>(bp + (size_t)48 * 4096);
        short8 b4 = *reinterpret_cast<const short8*>(bp + (size_t)64 * 4096);
        acc0 = __builtin_amdgcn_mfma_f32_16x16x32_bf16(af, b0, acc0, 0, 0, 0);
        acc1 = __builtin_amdgcn_mfma_f32_16x16x32_bf16(af, b1, acc1, 0, 0, 0);
        acc2 = __builtin_amdgcn_mfma_f32_16x16x32_bf16(af, b2, acc2, 0, 0, 0);
        acc3 = __builtin_amdgcn_mfma_f32_16x16x32_bf16(af, b3, acc3, 0, 0, 0);
        acc4 = __builtin_amdgcn_mfma_f32_16x16x32_bf16(af, b4, acc4, 0, 0, 0);
    }

    const int rbase = (lane >> 4) * 4;
    float* Pb = P + (size_t)ks * PS2;
#define STORE(ACC, T) do {                                              \
        int col = n0 + (T) * 16 + lrow;                                 \
        if (col < 450) {                                                \
            _Pragma("unroll")                                           \
            for (int r = 0; r < 4; ++r) {                               \
                int m = m0 + rbase + r;                                 \
                Pb[(size_t)(m >> 2) * 1800 + (m & 3) * 450 + col] = ACC[r]; \
            }                                                           \
        }                                                               \
    } while (0)
    STORE(acc0, 0); STORE(acc1, 1); STORE(acc2, 2); STORE(acc3, 3); STORE(acc4, 4);
#undef STORE
}

// -------- K3: attention (S=4 causal) + Wo + dense head (MKS=4 reduce) -------
__global__ __launch_bounds__(256) void k3_attn(const float* __restrict__ Wo,
    const float* __restrict__ d1w, const float* __restrict__ d1b,
    const float* __restrict__ d2w, const float* __restrict__ d2b,
    const float* __restrict__ d3w, const float* __restrict__ d3b,
    const float* __restrict__ ws, float* __restrict__ out)
{
    __shared__ float Qs[5][4][30], Ks2[5][4][30], Vs[5][4][30];
    __shared__ float sc[5][4][4];
    __shared__ float ob[4][150];
    __shared__ float hb[120], h1[10], h2[10];
    const int tid = threadIdx.x;
    const int b = blockIdx.x;
    const float* P = ws + WS_P + (size_t)b * 1800;

    for (int idx = tid; idx < 1800; idx += 256) {
        float val = 0.f;
#pragma unroll
        for (int ks = 0; ks < MKS; ++ks)
            val += P[(size_t)ks * PS2 + idx];
        int s = idx / 450, n = idx % 450;
        int proj = n / 150, hh = (n % 150) / 30, e = n % 30;
        if (proj == 0)      Qs[hh][s][e] = val;
        else if (proj == 1) Ks2[hh][s][e] = val;
        else                Vs[hh][s][e] = val;
    }
    __syncthreads();

    if (tid < 80) {
        int hh = tid >> 4, s = (tid >> 2) & 3, t = tid & 3;
        float a = 0.f;
        if (t <= s) {
            for (int e = 0; e < 30; ++e) a += Qs[hh][s][e] * Ks2[hh][t][e];
            a *= (1.0f / sqrtf(30.0f));
        }
        sc[hh][s][t] = a;
    }
    __syncthreads();

    if (tid < 20) {
        int hh = tid / 4, s = tid % 4;
        float m = -1e30f;
        for (int t = 0; t <= s; ++t) m = fmaxf(m, sc[hh][s][t]);
        float ex[4]; float den = 0.f;
        for (int t = 0; t <= s; ++t) { ex[t] = expf(sc[hh][s][t] - m); den += ex[t]; }
        for (int t = 0; t < 4; ++t) sc[hh][s][t] = (t <= s) ? ex[t] / den : 0.f;
    }
    __syncthreads();

    for (int idx = tid; idx < 600; idx += 256) {
        int s = idx / 150, j = idx % 150, hh = j / 30, e = j % 30;
        float a = 0.f;
        for (int t = 0; t < 4; ++t) a += sc[hh][s][t] * Vs[hh][t][e];
        ob[s][j] = a;
    }
    __syncthreads();

    if (tid < 120) {
        int s = tid / 30, e2 = tid % 30;
        float a = 0.f;
        for (int j = 0; j < 150; ++j) a += ob[s][j] * Wo[j * 30 + e2];
        hb[s * 30 + e2] = a;
    }
    __syncthreads();

    if (tid < 10) {
        float a = d1b[tid];
        for (int i = 0; i < 120; ++i) a += hb[i] * d1w[i * 10 + tid];
        h1[tid] = a > 0.f ? a : 0.2f * a;
    }
    __syncthreads();
    if (tid < 10) {
        float a = d2b[tid];
        for (int i = 0; i < 10; ++i) a += h1[i] * d2w[i * 10 + tid];
        h2[tid] = a > 0.f ? a : 0.2f * a;
    }
    __syncthreads();
    if (tid == 0) {
        float a = d3b[0];
        for (int i = 0; i < 10; ++i) a += h2[i] * d3w[i];
        out[b] = 1.f / (1.f + expf(-a));
    }
}

extern "C" void kernel_launch(void* const* d_in, const int* in_sizes, int n_in,
                              void* d_out, int out_size, void* d_ws, size_t ws_size,
                              hipStream_t stream)
{
    const int*   tokens = (const int*)d_in[0];
    const float* c1w = (const float*)d_in[1];
    const float* c1b = (const float*)d_in[2];
    const float* c2w = (const float*)d_in[3];
    const float* c2b = (const float*)d_in[4];
    const float* Wq  = (const float*)d_in[5];
    const float* Wk  = (const float*)d_in[6];
    const float* Wv  = (const float*)d_in[7];
    const float* Wo  = (const float*)d_in[8];
    const float* d1w = (const float*)d_in[9];
    const float* d1b = (const float*)d_in[10];
    const float* d2w = (const float*)d_in[11];
    const float* d2b = (const float*)d_in[12];
    const float* d3w = (const float*)d_in[13];
    const float* d3b = (const float*)d_in[14];
    float* ws = (float*)d_ws;
    float* out = (float*)d_out;

    k0_build<<<14, 256, 0, stream>>>(c1w, c1b, c2w, c2b, ws);
    k1_convpool<<<NB_K1 + WBBLK + PADABLK, 256, 0, stream>>>(tokens, Wq, Wk, Wv, ws, ws);
    k2_mfma<<<16 * 6 * MKS, 256, 0, stream>>>(
        reinterpret_cast<const unsigned short*>(ws + WS_A),
        reinterpret_cast<const unsigned short*>(ws + WS_WB),
        ws + WS_P);
    k3_attn<<<Bb, 256, 0, stream>>>(Wo, d1w, d1b, d2w, d2b, d3w, d3b, ws, out);
}